// Round 3
// baseline (1768.051 us; speedup 1.0000x reference)
//
#include <hip/hip_runtime.h>

#define D 64
#define SCAN_T 256
#define SCAN_E 4
#define CHUNK (SCAN_T * SCAN_E)   // 1024 elements per scan block
#define BSHIFT 8                  // 256 rows per bucket
#define BROWS (1 << BSHIFT)

// ---------- CSR build ----------

__global__ __launch_bounds__(256) void hist_rows(
    const int* __restrict__ rows, int* __restrict__ cnt, int nedges)
{
    int e = blockIdx.x * 256 + threadIdx.x;
    if (e < nedges) atomicAdd(&cnt[rows[e]], 1);
}

// per-chunk exclusive scan (in-place) + chunk totals
__global__ __launch_bounds__(SCAN_T) void scan_chunks(
    int* __restrict__ A, int n, int* __restrict__ bsums)
{
    __shared__ int lds[SCAN_T];
    int t = threadIdx.x;
    int base = blockIdx.x * CHUNK + t * SCAN_E;
    int v[SCAN_E];
    int s = 0;
    #pragma unroll
    for (int i = 0; i < SCAN_E; i++) { v[i] = (base + i < n) ? A[base + i] : 0; s += v[i]; }
    lds[t] = s;
    __syncthreads();
    for (int ofs = 1; ofs < SCAN_T; ofs <<= 1) {
        int x = (t >= ofs) ? lds[t - ofs] : 0;
        __syncthreads();
        lds[t] += x;
        __syncthreads();
    }
    if (t == SCAN_T - 1) bsums[blockIdx.x] = lds[t];
    int run = lds[t] - s;
    #pragma unroll
    for (int i = 0; i < SCAN_E; i++) { int x = v[i]; if (base + i < n) A[base + i] = run; run += x; }
}

__global__ __launch_bounds__(1024) void scan_bsums(int* __restrict__ bsums, int nb)
{
    __shared__ int lds[1024];
    int t = threadIdx.x;
    int v = (t < nb) ? bsums[t] : 0;
    lds[t] = v;
    __syncthreads();
    for (int ofs = 1; ofs < 1024; ofs <<= 1) {
        int x = (t >= ofs) ? lds[t - ofs] : 0;
        __syncthreads();
        lds[t] += x;
        __syncthreads();
    }
    if (t < nb) bsums[t] = lds[t] - v;
}

__global__ __launch_bounds__(SCAN_T) void add_bsums(
    int* __restrict__ A, int n, const int* __restrict__ bsums)
{
    int t = threadIdx.x;
    int base = blockIdx.x * CHUNK + t * SCAN_E;
    int add = bsums[blockIdx.x];
    #pragma unroll
    for (int i = 0; i < SCAN_E; i++) if (base + i < n) A[base + i] += add;
}

// B[b] = rowstart of first row in bucket b  (A holds exclusive row prefix)
__global__ __launch_bounds__(256) void init_buckets(
    const int* __restrict__ A, int* __restrict__ B, int nbuckets, int n)
{
    int b = blockIdx.x * 256 + threadIdx.x;
    if (b < nbuckets) B[b] = A[(size_t)b << BSHIFT];
}

// Phase A: bin edges by row>>BSHIFT into staged[], packed (rowlocal<<19)|col, val
__global__ __launch_bounds__(256) void bin_edges(
    const int* __restrict__ rows, const int* __restrict__ cols,
    const float* __restrict__ vals, int* __restrict__ bcur,
    int2* __restrict__ staged, int nedges)
{
    int e = blockIdx.x * 256 + threadIdx.x;
    if (e >= nedges) return;
    int r = rows[e];
    int b = r >> BSHIFT;
    int pos = atomicAdd(&bcur[b], 1);
    staged[pos] = make_int2(cols[e] | ((r & (BROWS - 1)) << 19), __float_as_int(vals[e]));
}

// Phase B: one block per bucket; scatter staged records to final CSR slots.
// cur (=A) bumps from rowstart to rowend; only this block touches its rows.
__global__ __launch_bounds__(256) void bucket_scatter(
    int* __restrict__ cur, const int* __restrict__ bend,
    const int2* __restrict__ staged, int2* __restrict__ pairs, int n)
{
    __shared__ int sh[2];
    int b = blockIdx.x;
    if (threadIdx.x == 0) {
        sh[0] = cur[(size_t)b << BSHIFT];  // bucket start (read before any bump)
        sh[1] = bend[b];                   // bucket end (phase-A final cursor)
    }
    __syncthreads();
    int start = sh[0], end = sh[1];
    int rowbase = b << BSHIFT;
    for (int i = start + threadIdx.x; i < end; i += 256) {
        int2 p = staged[i];
        int row = rowbase + ((unsigned)p.x >> 19);
        int pos = atomicAdd(&cur[row], 1);
        pairs[pos] = make_int2(p.x & 0x7FFFF, p.y);
    }
}

// ---------- gather-style CSR spmm ----------
template <bool FUSED>
__global__ __launch_bounds__(256) void spmm_csr(
    const int* __restrict__ endp, const int2* __restrict__ pairs,
    const float* __restrict__ srcA, const float* __restrict__ srcB, int split,
    const float* __restrict__ u, const float* __restrict__ it, int user,
    const float* __restrict__ prev, float* __restrict__ out, int n)
{
    int row = blockIdx.x * 16 + (threadIdx.x >> 4);
    if (row >= n) return;
    int l = threadIdx.x & 15;
    int start = row ? endp[row - 1] : 0;
    int end = endp[row];
    float ax = 0.f, ay = 0.f, az = 0.f, aw = 0.f;
    for (int e = start; e < end; ++e) {
        int2 p = pairs[e];
        int col = p.x;
        float v = __int_as_float(p.y);
        const float* src = (col < split) ? srcA + (size_t)col * D
                                         : srcB + (size_t)(col - split) * D;
        float4 x = *(const float4*)(src + l * 4);
        ax = fmaf(v, x.x, ax);
        ay = fmaf(v, x.y, ay);
        az = fmaf(v, x.z, az);
        aw = fmaf(v, x.w, aw);
    }
    float* o = out + (size_t)row * D + l * 4;
    if (FUSED) {
        const float* e0 = (row < user) ? u + (size_t)row * D
                                       : it + (size_t)(row - user) * D;
        float4 b0 = *(const float4*)(e0 + l * 4);
        float4 b1 = *(const float4*)o;                                // e1
        float4 b2 = *(const float4*)(prev + (size_t)row * D + l * 4); // e2
        ax += b0.x + b1.x + b2.x;
        ay += b0.y + b1.y + b2.y;
        az += b0.z + b1.z + b2.z;
        aw += b0.w + b1.w + b2.w;
    }
    *(float4*)o = make_float4(ax, ay, az, aw);
}

// ---------- launch ----------

static inline size_t alignup(size_t x) { return (x + 255) & ~(size_t)255; }

extern "C" void kernel_launch(void* const* d_in, const int* in_sizes, int n_in,
                              void* d_out, int out_size, void* d_ws, size_t ws_size,
                              hipStream_t stream) {
    const int*   rows = (const int*)  d_in[0];
    const int*   cols = (const int*)  d_in[1];
    const float* vals = (const float*)d_in[2];
    const float* u    = (const float*)d_in[3];
    const float* it   = (const float*)d_in[4];

    const int nedges = in_sizes[0];
    const int user   = in_sizes[3] / D;
    const int item   = in_sizes[4] / D;
    const int n      = user + item;
    const int nbuckets = (n + BROWS - 1) / BROWS;

    float* out = (float*)d_out;

    // workspace carve
    char* w = (char*)d_ws;
    int*  A     = (int*)w;  w += alignup((size_t)n * sizeof(int));
    int*  bsums = (int*)w;  w += alignup(4096);
    int*  B     = (int*)w;  w += alignup((size_t)nbuckets * sizeof(int));
    int2* pairs = (int2*)w; w += alignup((size_t)nedges * sizeof(int2));
    float* buf2 = (float*)w;                  // n * D floats (spmm temp)
    int2* staged = (int2*)buf2;               // overlaps buf2: only live pre-spmm

    const int nb = (n + CHUNK - 1) / CHUNK;
    const int eblocks = (nedges + 255) / 256;
    const int sblocks = (n + 15) / 16;

    // CSR build
    hipMemsetAsync(A, 0, (size_t)n * sizeof(int), stream);
    hist_rows<<<eblocks, 256, 0, stream>>>(rows, A, nedges);
    scan_chunks<<<nb, SCAN_T, 0, stream>>>(A, n, bsums);
    scan_bsums<<<1, 1024, 0, stream>>>(bsums, nb);
    add_bsums<<<nb, SCAN_T, 0, stream>>>(A, n, bsums);
    init_buckets<<<(nbuckets + 255) / 256, 256, 0, stream>>>(A, B, nbuckets, n);
    bin_edges<<<eblocks, 256, 0, stream>>>(rows, cols, vals, B, staged, nedges);
    bucket_scatter<<<nbuckets, 256, 0, stream>>>(A, B, staged, pairs, n);

    // out = e1 = spmm(e0)
    spmm_csr<false><<<sblocks, 256, 0, stream>>>(
        A, pairs, u, it, user, nullptr, nullptr, user, nullptr, out, n);
    // buf2 = e2 = spmm(e1)
    spmm_csr<false><<<sblocks, 256, 0, stream>>>(
        A, pairs, out, out + (size_t)user * D, user, nullptr, nullptr, user, nullptr, buf2, n);
    // out = e0 + e1 + e2 + spmm(e2)
    spmm_csr<true><<<sblocks, 256, 0, stream>>>(
        A, pairs, buf2, buf2 + (size_t)user * D, user, u, it, user, buf2, out, n);
}

// Round 4
// 1167.320 us; speedup vs baseline: 1.5146x; 1.5146x over previous
//
#include <hip/hip_runtime.h>

#define D 64
#define SCAN_T 256
#define SCAN_E 4
#define CHUNK (SCAN_T * SCAN_E)   // 1024 elements per scan block

#define SB_SHIFT 11               // 2048 rows per coarse bucket
#define ROWS_PB (1 << SB_SHIFT)
#define P1_T 256
#define P1_E 32
#define P1_EPB (P1_T * P1_E)      // 8192 edges per partition block
#define SPLIT 8                   // pass-2 blocks per bucket

// ---------- CSR build ----------

__global__ __launch_bounds__(256) void hist_rows(
    const int* __restrict__ rows, int* __restrict__ cnt, int nedges)
{
    int e = blockIdx.x * 256 + threadIdx.x;
    if (e < nedges) atomicAdd(&cnt[rows[e]], 1);
}

__global__ __launch_bounds__(SCAN_T) void scan_chunks(
    int* __restrict__ A, int n, int* __restrict__ bsums)
{
    __shared__ int lds[SCAN_T];
    int t = threadIdx.x;
    int base = blockIdx.x * CHUNK + t * SCAN_E;
    int v[SCAN_E];
    int s = 0;
    #pragma unroll
    for (int i = 0; i < SCAN_E; i++) { v[i] = (base + i < n) ? A[base + i] : 0; s += v[i]; }
    lds[t] = s;
    __syncthreads();
    for (int ofs = 1; ofs < SCAN_T; ofs <<= 1) {
        int x = (t >= ofs) ? lds[t - ofs] : 0;
        __syncthreads();
        lds[t] += x;
        __syncthreads();
    }
    if (t == SCAN_T - 1) bsums[blockIdx.x] = lds[t];
    int run = lds[t] - s;
    #pragma unroll
    for (int i = 0; i < SCAN_E; i++) { int x = v[i]; if (base + i < n) A[base + i] = run; run += x; }
}

__global__ __launch_bounds__(1024) void scan_bsums(int* __restrict__ bsums, int nb)
{
    __shared__ int lds[1024];
    int t = threadIdx.x;
    int v = (t < nb) ? bsums[t] : 0;
    lds[t] = v;
    __syncthreads();
    for (int ofs = 1; ofs < 1024; ofs <<= 1) {
        int x = (t >= ofs) ? lds[t - ofs] : 0;
        __syncthreads();
        lds[t] += x;
        __syncthreads();
    }
    if (t < nb) bsums[t] = lds[t] - v;
}

__global__ __launch_bounds__(SCAN_T) void add_bsums(
    int* __restrict__ A, int n, const int* __restrict__ bsums)
{
    int t = threadIdx.x;
    int base = blockIdx.x * CHUNK + t * SCAN_E;
    int add = bsums[blockIdx.x];
    #pragma unroll
    for (int i = 0; i < SCAN_E; i++) if (base + i < n) A[base + i] += add;
}

// B[b] = CSR start of bucket b; gcur starts there too. B[nsb] = nedges.
__global__ __launch_bounds__(256) void init_buckets(
    const int* __restrict__ A, int* __restrict__ B, int* __restrict__ gcur,
    int nsb, int nedges)
{
    int b = blockIdx.x * 256 + threadIdx.x;
    if (b < nsb) { int v = A[(size_t)b << SB_SHIFT]; B[b] = v; gcur[b] = v; }
    else if (b == nsb) B[b] = nedges;
}

// Pass 1: LDS-histogram partition into coarse buckets.
// Per block: hist 8192 edges over <=256 buckets in LDS, reserve each bucket's
// range with ONE global atomic, write records at gbase+rank (448B chunks).
__global__ __launch_bounds__(P1_T) void partition_edges(
    const int* __restrict__ rows, const int* __restrict__ cols,
    const float* __restrict__ vals, int* __restrict__ gcur,
    int2* __restrict__ staged, int nedges, int nsb)
{
    __shared__ int hist[256];
    __shared__ int gbase[256];
    int t = threadIdx.x;
    int base = blockIdx.x * P1_EPB;
    if (t < nsb) hist[t] = 0;
    __syncthreads();
    int pk[P1_E];
    #pragma unroll
    for (int i = 0; i < P1_E; i++) {
        int e = base + i * P1_T + t;
        if (e < nedges) {
            int b = rows[e] >> SB_SHIFT;
            int rank = atomicAdd(&hist[b], 1);
            pk[i] = (rank << 8) | b;      // rank<8192 (13b), b<256 (8b)
        } else pk[i] = -1;
    }
    __syncthreads();
    if (t < nsb) {
        int c = hist[t];
        gbase[t] = c ? atomicAdd(&gcur[t], c) : 0;
    }
    __syncthreads();
    #pragma unroll
    for (int i = 0; i < P1_E; i++) {
        if (pk[i] < 0) continue;
        int e = base + i * P1_T + t;
        int b = pk[i] & 255;
        int rank = pk[i] >> 8;
        int rl = rows[e] & (ROWS_PB - 1);
        staged[gbase[b] + rank] = make_int2((rl << 19) | cols[e], __float_as_int(vals[e]));
    }
}

// Pass 2: per (bucket, slice): scatter staged records to final CSR slots.
// Destination window = one bucket's CSR range (~260KB) -> L2-resident.
__global__ __launch_bounds__(256) void csr_scatter(
    int* __restrict__ cur, const int* __restrict__ B,
    const int2* __restrict__ staged, int2* __restrict__ pairs)
{
    int b = blockIdx.x / SPLIT;
    int s = blockIdx.x % SPLIT;
    int segs = B[b], sege = B[b + 1];
    int len = sege - segs;
    int i0 = segs + (int)((long long)len * s / SPLIT);
    int i1 = segs + (int)((long long)len * (s + 1) / SPLIT);
    int rowbase = b << SB_SHIFT;
    for (int i = i0 + threadIdx.x; i < i1; i += 256) {
        int2 p = staged[i];
        int row = rowbase + ((unsigned)p.x >> 19);
        int pos = atomicAdd(&cur[row], 1);
        pairs[pos] = make_int2(p.x & 0x7FFFF, p.y);
    }
}

// ---------- gather-style CSR spmm ----------
template <bool FUSED>
__global__ __launch_bounds__(256) void spmm_csr(
    const int* __restrict__ endp, const int2* __restrict__ pairs,
    const float* __restrict__ srcA, const float* __restrict__ srcB, int split,
    const float* __restrict__ u, const float* __restrict__ it, int user,
    const float* __restrict__ prev, float* __restrict__ out, int n)
{
    int row = blockIdx.x * 16 + (threadIdx.x >> 4);
    if (row >= n) return;
    int l = threadIdx.x & 15;
    int start = row ? endp[row - 1] : 0;
    int end = endp[row];
    float ax = 0.f, ay = 0.f, az = 0.f, aw = 0.f;
    for (int e = start; e < end; ++e) {
        int2 p = pairs[e];
        int col = p.x;
        float v = __int_as_float(p.y);
        const float* src = (col < split) ? srcA + (size_t)col * D
                                         : srcB + (size_t)(col - split) * D;
        float4 x = *(const float4*)(src + l * 4);
        ax = fmaf(v, x.x, ax);
        ay = fmaf(v, x.y, ay);
        az = fmaf(v, x.z, az);
        aw = fmaf(v, x.w, aw);
    }
    float* o = out + (size_t)row * D + l * 4;
    if (FUSED) {
        const float* e0 = (row < user) ? u + (size_t)row * D
                                       : it + (size_t)(row - user) * D;
        float4 b0 = *(const float4*)(e0 + l * 4);
        float4 b1 = *(const float4*)o;                                // e1
        float4 b2 = *(const float4*)(prev + (size_t)row * D + l * 4); // e2
        ax += b0.x + b1.x + b2.x;
        ay += b0.y + b1.y + b2.y;
        az += b0.z + b1.z + b2.z;
        aw += b0.w + b1.w + b2.w;
    }
    *(float4*)o = make_float4(ax, ay, az, aw);
}

// ---------- launch ----------

static inline size_t alignup(size_t x) { return (x + 255) & ~(size_t)255; }

extern "C" void kernel_launch(void* const* d_in, const int* in_sizes, int n_in,
                              void* d_out, int out_size, void* d_ws, size_t ws_size,
                              hipStream_t stream) {
    const int*   rows = (const int*)  d_in[0];
    const int*   cols = (const int*)  d_in[1];
    const float* vals = (const float*)d_in[2];
    const float* u    = (const float*)d_in[3];
    const float* it   = (const float*)d_in[4];

    const int nedges = in_sizes[0];
    const int user   = in_sizes[3] / D;
    const int item   = in_sizes[4] / D;
    const int n      = user + item;
    const int nsb    = (n + ROWS_PB - 1) >> SB_SHIFT;   // 147 coarse buckets

    float* out = (float*)d_out;

    // workspace carve
    char* w = (char*)d_ws;
    int*  A     = (int*)w;  w += alignup((size_t)n * sizeof(int));
    int*  bsums = (int*)w;  w += alignup(4096);
    int*  B     = (int*)w;  w += alignup((size_t)(nsb + 1) * sizeof(int));
    int*  gcur  = (int*)w;  w += alignup((size_t)nsb * sizeof(int));
    int2* pairs = (int2*)w; w += alignup((size_t)nedges * sizeof(int2));
    float* buf2 = (float*)w;                 // n * D floats (spmm temp)
    int2* staged = (int2*)buf2;              // overlaps buf2: dead after pass 2

    const int nb = (n + CHUNK - 1) / CHUNK;
    const int eblocks = (nedges + 255) / 256;
    const int p1blocks = (nedges + P1_EPB - 1) / P1_EPB;
    const int sblocks = (n + 15) / 16;

    // CSR build
    hipMemsetAsync(A, 0, (size_t)n * sizeof(int), stream);
    hist_rows<<<eblocks, 256, 0, stream>>>(rows, A, nedges);
    scan_chunks<<<nb, SCAN_T, 0, stream>>>(A, n, bsums);
    scan_bsums<<<1, 1024, 0, stream>>>(bsums, nb);
    add_bsums<<<nb, SCAN_T, 0, stream>>>(A, n, bsums);
    init_buckets<<<(nsb + 256) / 256 + 1, 256, 0, stream>>>(A, B, gcur, nsb, nedges);
    partition_edges<<<p1blocks, P1_T, 0, stream>>>(rows, cols, vals, gcur, staged, nedges, nsb);
    csr_scatter<<<nsb * SPLIT, 256, 0, stream>>>(A, B, staged, pairs);

    // out = e1 = spmm(e0)
    spmm_csr<false><<<sblocks, 256, 0, stream>>>(
        A, pairs, u, it, user, nullptr, nullptr, user, nullptr, out, n);
    // buf2 = e2 = spmm(e1)
    spmm_csr<false><<<sblocks, 256, 0, stream>>>(
        A, pairs, out, out + (size_t)user * D, user, nullptr, nullptr, user, nullptr, buf2, n);
    // out = e0 + e1 + e2 + spmm(e2)
    spmm_csr<true><<<sblocks, 256, 0, stream>>>(
        A, pairs, buf2, buf2 + (size_t)user * D, user, u, it, user, buf2, out, n);
}